// Round 9
// baseline (603.460 us; speedup 1.0000x reference)
//
#include <hip/hip_runtime.h>

// Problem constants
#define DM     1024
#define NHEADS 16
#define DK     64
#define NB     8
#define SEQ    1024
#define MROWS  (NB * SEQ)            // 8192
#define NQ     ((size_t)MROWS * DM)  // 8M elements

typedef unsigned short u16;
typedef __attribute__((ext_vector_type(8))) _Float16 f16x8;
typedef __attribute__((ext_vector_type(8))) short  short8v;
typedef __attribute__((ext_vector_type(4))) float  f32x4;

typedef const __attribute__((address_space(1))) void* gas_ptr;
typedef __attribute__((address_space(3))) void*       las_ptr;

__device__ __forceinline__ void load_lds16(const void* g, void* l) {
    __builtin_amdgcn_global_load_lds((gas_ptr)g, (las_ptr)l, 16, 0, 0);
}
__device__ __forceinline__ void load_lds4(const void* g, void* l) {
    __builtin_amdgcn_global_load_lds((gas_ptr)g, (las_ptr)l, 4, 0, 0);
}

__device__ __forceinline__ u16 f16_bits(float x) {
    union { _Float16 h; u16 u; } c;
    c.h = (_Float16)x;  // v_cvt_f16_f32, RNE
    return c.u;
}
__device__ __forceinline__ float f16_val(u16 u) {
    union { _Float16 h; u16 u; } c;
    c.u = u;
    return (float)c.h;
}

// ---------------------------------------------------------------------------
// conv_cast3: q,k,v fp32 -> single f16 (the split lives on the weight side).
// ---------------------------------------------------------------------------
__global__ __launch_bounds__(256)
void conv_cast3(const float* __restrict__ q, const float* __restrict__ k,
                const float* __restrict__ v, u16* __restrict__ qo,
                u16* __restrict__ ko, u16* __restrict__ vo)
{
    const int z = blockIdx.z;
    const float* in = (z == 0) ? q : (z == 1) ? k : v;
    u16* o = (z == 0) ? qo : (z == 1) ? ko : vo;
    size_t i8 = ((size_t)blockIdx.x * 256 + threadIdx.x) * 8;
    float4 x0 = *(const float4*)(in + i8);
    float4 x1 = *(const float4*)(in + i8 + 4);
    float xs[8] = {x0.x, x0.y, x0.z, x0.w, x1.x, x1.y, x1.z, x1.w};
    short8v r;
#pragma unroll
    for (int j = 0; j < 8; ++j) r[j] = (short)f16_bits(xs[j]);
    *(short8v*)(o + i8) = r;
}

// ---------------------------------------------------------------------------
// conv_w: W [k][n] fp32 -> Wt hi/lo [n][k] f16 (transposed split), 4 weights.
// ---------------------------------------------------------------------------
__global__ __launch_bounds__(256)
void conv_w(const float* __restrict__ W0, const float* __restrict__ W1,
            const float* __restrict__ W2, const float* __restrict__ W3,
            u16* __restrict__ hiB, u16* __restrict__ loB)
{
    __shared__ float Wf[32][68];
    const int t = threadIdx.x;
    const int n0 = blockIdx.x * 64, k0 = blockIdx.y * 32, z = blockIdx.z;
    const float* W = (z == 0) ? W0 : (z == 1) ? W1 : (z == 2) ? W2 : W3;
    u16* hi = hiB + (size_t)z * DM * DM;
    u16* lo = loB + (size_t)z * DM * DM;

#pragma unroll
    for (int p = 0; p < 2; ++p) {
        int fid = p * 256 + t;
        int kk = fid >> 4, c4 = fid & 15;
        *(float4*)&Wf[kk][c4 * 4] =
            *(const float4*)(W + (size_t)(k0 + kk) * DM + n0 + c4 * 4);
    }
    __syncthreads();

    const int n = t >> 2, g = t & 3;
    short8v vh, vl;
#pragma unroll
    for (int j = 0; j < 8; ++j) {
        float x = Wf[g * 8 + j][n];
        u16 h = f16_bits(x);
        vh[j] = (short)h;
        vl[j] = (short)f16_bits(x - f16_val(h));
    }
    size_t off = (size_t)(n0 + n) * DM + k0 + g * 8;
    *(short8v*)(hi + off) = vh;
    *(short8v*)(lo + off) = vl;
}

// ---------------------------------------------------------------------------
// 2-product f16 MFMA GEMM: C = A_f16 @ (B_hi + B_lo)^T + bias.
// A f16 [m][k], B hi/lo f16 [n][k]. 128x128 tile, 4 waves, BK=32.
// Modes: 0 = fp32 out (direct); 1 = f16 hi/lo pair (LDS-bounced, coalesced);
// 2 = single f16 (bounced); 3 = single f16 TRANSPOSED to Vt[b,h,d,s].
// __launch_bounds__(256,3): cap VGPR <=170 so 3 blocks/CU stay resident
// (r7 post-mortem: 172 VGPR -> 1 block/CU -> MfmaUtil 22%).
// ---------------------------------------------------------------------------
#define PITCH 136
__device__ __forceinline__ void gemm2_body(
    const u16* __restrict__ Ag, const u16* __restrict__ Bgh,
    const u16* __restrict__ Bgl, const float* __restrict__ bias, int mode,
    float* __restrict__ Cf, u16* __restrict__ C1, u16* __restrict__ C2)
{
    __shared__ __align__(16) u16 smem[128 * PITCH];  // 34 KB
    u16* const Af = smem;          // 4096 u16
    u16* const Bh = smem + 4096;
    u16* const Bl = smem + 8192;

    const int t = threadIdx.x, lane = t & 63, wid = t >> 6;
    const int m0 = blockIdx.x * 128, n0 = blockIdx.y * 128;
    const int wm0 = (wid >> 1) * 64, wn0 = (wid & 1) * 64;
    const int ln = lane & 15, blk = lane >> 4;

    // staging: 24 one-KB chunks (Af:8, Bh:8, Bl:8), 6 per wave.
    const int lr = lane >> 2, sl = lane & 3;
    const int gg = sl ^ ((lr >> 1) & 3);  // source-side XOR swizzle
    const u16* gA[6];
    u16* lA[6];
#pragma unroll
    for (int i = 0; i < 6; ++i) {
        int c = wid * 6 + i, sub = c & 7;
        const u16* gsrc; u16* lbuf; int r0;
        if (c < 8)       { gsrc = Ag;  lbuf = Af; r0 = m0; }
        else if (c < 16) { gsrc = Bgh; lbuf = Bh; r0 = n0; }
        else             { gsrc = Bgl; lbuf = Bl; r0 = n0; }
        gA[i] = gsrc + (size_t)(r0 + sub * 16 + lr) * DM + gg * 8;
        lA[i] = lbuf + sub * 512;
    }

    f32x4 zero4 = {0.f, 0.f, 0.f, 0.f};
    f32x4 acc[4][4];
#pragma unroll
    for (int i = 0; i < 4; ++i)
#pragma unroll
        for (int j = 0; j < 4; ++j) acc[i][j] = zero4;

    for (int kt = 0; kt < 1024; kt += 32) {
        __syncthreads();
#pragma unroll
        for (int i = 0; i < 6; ++i) load_lds16(gA[i] + kt, lA[i]);
        __syncthreads();

        f16x8 bh[4], bl[4];
#pragma unroll
        for (int bn = 0; bn < 4; ++bn) {
            int rn = wn0 + bn * 16 + ln;
            int off = rn * 32 + ((blk ^ ((rn >> 1) & 3)) << 3);
            bh[bn] = *(const f16x8*)(Bh + off);
            bl[bn] = *(const f16x8*)(Bl + off);
        }
#pragma unroll
        for (int am = 0; am < 4; ++am) {
            int rm = wm0 + am * 16 + ln;
            int off = rm * 32 + ((blk ^ ((rm >> 1) & 3)) << 3);
            f16x8 af = *(const f16x8*)(Af + off);
#pragma unroll
            for (int bn = 0; bn < 4; ++bn) {
                acc[am][bn] = __builtin_amdgcn_mfma_f32_16x16x32_f16(
                    af, bh[bn], acc[am][bn], 0, 0, 0);
                acc[am][bn] = __builtin_amdgcn_mfma_f32_16x16x32_f16(
                    af, bl[bn], acc[am][bn], 0, 0, 0);
            }
        }
    }

    // ---- epilogue (C/D layout: col = lane&15, row = (lane>>4)*4 + reg) ----
    if (mode == 0) {
#pragma unroll
        for (int bn = 0; bn < 4; ++bn) {
            int coll = wn0 + bn * 16 + ln;
            float bs = bias[n0 + coll];
#pragma unroll
            for (int am = 0; am < 4; ++am)
#pragma unroll
                for (int r = 0; r < 4; ++r) {
                    int rowl = wm0 + am * 16 + blk * 4 + r;
                    Cf[(size_t)(m0 + rowl) * DM + n0 + coll] =
                        acc[am][bn][r] + bs;
                }
        }
        return;
    }

    __syncthreads();  // K-loop LDS reads done before smem reuse

    if (mode == 3) {
        // store TRANSPOSED into smem[col][row]; write Vt[b,h,d,s] coalesced
#pragma unroll
        for (int bn = 0; bn < 4; ++bn) {
            int coll = wn0 + bn * 16 + ln;
            float bs = bias[n0 + coll];
#pragma unroll
            for (int am = 0; am < 4; ++am)
#pragma unroll
                for (int r = 0; r < 4; ++r) {
                    int rowl = wm0 + am * 16 + blk * 4 + r;
                    smem[coll * PITCH + rowl] = f16_bits(acc[am][bn][r] + bs);
                }
        }
        __syncthreads();
        const int bq_ = m0 >> 10, s0_ = m0 & 1023, h0_ = n0 >> 6;
#pragma unroll
        for (int p = 0; p < 8; ++p) {
            int c = p * 256 + t;           // 0..2047
            int h_l = c >> 10;             // 0..1
            int d   = (c >> 4) & 63;
            int sc  = c & 15;
            int scp = (sc + ((d & 3) << 2)) & 15;  // bank de-phase
            short8v rd = *(const short8v*)(smem + (h_l * 64 + d) * PITCH +
                                           scp * 8);
            *(short8v*)(C1 +
                        ((size_t)(bq_ * NHEADS + h0_ + h_l) * DK + d) * SEQ +
                        s0_ + scp * 8) = rd;
        }
        return;
    }

    // modes 1/2: natural layout bounce; mode 1 keeps residual for the lo pass
#pragma unroll
    for (int bn = 0; bn < 4; ++bn) {
        int coll = wn0 + bn * 16 + ln;
        float bs = bias[n0 + coll];
#pragma unroll
        for (int am = 0; am < 4; ++am)
#pragma unroll
            for (int r = 0; r < 4; ++r) {
                int rowl = wm0 + am * 16 + blk * 4 + r;
                float v = acc[am][bn][r] + bs;
                u16 hb = f16_bits(v);
                smem[rowl * PITCH + coll] = hb;
                acc[am][bn][r] = v - f16_val(hb);  // residual
            }
    }
    __syncthreads();
#pragma unroll
    for (int p = 0; p < 8; ++p) {
        int f = p * 256 + t;
        int row = f >> 4, cc = f & 15;
        int ccp = (cc + ((row & 3) << 2)) & 15;
        short8v rd = *(const short8v*)(smem + row * PITCH + ccp * 8);
        *(short8v*)(C1 + (size_t)(m0 + row) * DM + n0 + ccp * 8) = rd;
    }
    if (mode == 1) {
        __syncthreads();
#pragma unroll
        for (int bn = 0; bn < 4; ++bn) {
            int coll = wn0 + bn * 16 + ln;
#pragma unroll
            for (int am = 0; am < 4; ++am)
#pragma unroll
                for (int r = 0; r < 4; ++r) {
                    int rowl = wm0 + am * 16 + blk * 4 + r;
                    smem[rowl * PITCH + coll] = f16_bits(acc[am][bn][r]);
                }
        }
        __syncthreads();
#pragma unroll
        for (int p = 0; p < 8; ++p) {
            int f = p * 256 + t;
            int row = f >> 4, cc = f & 15;
            int ccp = (cc + ((row & 3) << 2)) & 15;
            short8v rd = *(const short8v*)(smem + row * PITCH + ccp * 8);
            *(short8v*)(C2 + (size_t)(m0 + row) * DM + n0 + ccp * 8) = rd;
        }
    }
}

__global__ __launch_bounds__(256, 3)
void gemm_qkv(const u16* __restrict__ Aq, const u16* __restrict__ Ak,
              const u16* __restrict__ Av, const u16* __restrict__ Wqh,
              const u16* __restrict__ Wql, const u16* __restrict__ Wkh,
              const u16* __restrict__ Wkl, const u16* __restrict__ Wvh,
              const u16* __restrict__ Wvl, const float* __restrict__ bq,
              const float* __restrict__ bk, const float* __restrict__ bv,
              u16* __restrict__ Qh, u16* __restrict__ Ql,
              u16* __restrict__ Kf, u16* __restrict__ Vt)
{
    const int z = blockIdx.z;
    const u16* A  = (z == 0) ? Aq  : (z == 1) ? Ak  : Av;
    const u16* Bh = (z == 0) ? Wqh : (z == 1) ? Wkh : Wvh;
    const u16* Bl = (z == 0) ? Wql : (z == 1) ? Wkl : Wvl;
    const float* bias = (z == 0) ? bq : (z == 1) ? bk : bv;
    u16* C1 = (z == 0) ? Qh : (z == 1) ? Kf : Vt;
    u16* C2 = (z == 0) ? Ql : nullptr;
    gemm2_body(A, Bh, Bl, bias, (z == 0) ? 1 : (z == 1) ? 2 : 3,
               nullptr, C1, C2);
}

__global__ __launch_bounds__(256, 3)
void gemm_o(const u16* __restrict__ A, const u16* __restrict__ Bh,
            const u16* __restrict__ Bl, const float* __restrict__ bias,
            float* __restrict__ out)
{
    gemm2_body(A, Bh, Bl, bias, 0, out, nullptr, nullptr);
}

// ---------------------------------------------------------------------------
// attn_f16: flash attention on f16 MFMA. Q hi/lo in REGISTERS; K single f16 +
// V^T single f16 staged in LDS (source-XOR swizzled); QK^T = 2 products
// (qh·k + ql·k); defer-max online softmax with the 1/32 scale folded into
// exp; P in f16; epilogue LDS-bounced to coalesced short8 f16 stores.
// 128 q-rows/block, 4 waves x 32 q, KV tiles of 64. LDS ~25 KB.
// ---------------------------------------------------------------------------
#define OPITCH 72
__global__ __launch_bounds__(256, 3)
void attn_f16(const u16* __restrict__ Qh, const u16* __restrict__ Ql,
              const u16* __restrict__ Kf, const u16* __restrict__ Vtg,
              const int* __restrict__ mask, u16* __restrict__ Ao)
{
    __shared__ __align__(16) u16 asmem[12288];  // Ks|Vts|Ps; epi bounce 128x72
    __shared__ int msk_s[64];
    u16* const Ks  = asmem;           // 4096 u16
    u16* const Vts = asmem + 4096;    // 4096 u16

    const int t = threadIdx.x, lane = t & 63, wid = t >> 6;
    const int q0 = blockIdx.x * 128;
    const int h = blockIdx.y, b = blockIdx.z;
    const int ln = lane & 15, blk = lane >> 4;
    const int lr8 = lane >> 3;
    const int schk = (lane & 7) ^ lr8;

    // ---- Q fragments (hi/lo f16) straight to registers ----
    f16x8 qfh[2][2], qfl[2][2];
#pragma unroll
    for (int am = 0; am < 2; ++am) {
        int row = q0 + wid * 32 + am * 16 + ln;
        size_t base = (size_t)(b * SEQ + row) * DM + h * DK;
#pragma unroll
        for (int ks = 0; ks < 2; ++ks) {
            qfh[am][ks] = *(const f16x8*)(Qh + base + (ks * 4 + blk) * 8);
            qfl[am][ks] = *(const f16x8*)(Ql + base + (ks * 4 + blk) * 8);
        }
    }

    // ---- staging plan: 16 chunks (Ks:8, Vts:8), 4 per wave ----
    const u16* gA[4];
    u16* lA[4];
    size_t stp[4];
#pragma unroll
    for (int i = 0; i < 4; ++i) {
        int c = wid * 4 + i, sub = c & 7;
        if (c < 8) {
            gA[i] = Kf + ((size_t)(b * SEQ) + sub * 8 + lr8) * DM + h * DK +
                    schk * 8;
            lA[i] = Ks + sub * 512;
            stp[i] = (size_t)64 * DM;
        } else {
            gA[i] = Vtg + ((size_t)((b * NHEADS + h) * DK) + sub * 8 + lr8) *
                              SEQ +
                    schk * 8;
            lA[i] = Vts + sub * 512;
            stp[i] = 64;
        }
    }

    float m_i[2][4], l_i[2][4];
    f32x4 oacc[2][4];
    f32x4 zero4 = {0.f, 0.f, 0.f, 0.f};
#pragma unroll
    for (int am = 0; am < 2; ++am) {
#pragma unroll
        for (int r = 0; r < 4; ++r) { m_i[am][r] = -INFINITY; l_i[am][r] = 0.f; }
#pragma unroll
        for (int bn = 0; bn < 4; ++bn) oacc[am][bn] = zero4;
    }

    for (int kv0 = 0; kv0 < SEQ; kv0 += 64) {
        __syncthreads();
#pragma unroll
        for (int i = 0; i < 4; ++i) {
            load_lds16(gA[i], lA[i]);
            gA[i] += stp[i];
        }
        if (wid == 3)
            load_lds4(mask + (size_t)b * SEQ + kv0 + lane, (char*)msk_s);
        __syncthreads();

        int mvals[4];
#pragma unroll
        for (int ct = 0; ct < 4; ++ct) mvals[ct] = msk_s[ct * 16 + ln];

#pragma unroll
        for (int am = 0; am < 2; ++am) {
            // ---- QK^T: 2 products (qh·k + ql·k) ----
            f32x4 s[4];
#pragma unroll
            for (int ct = 0; ct < 4; ++ct) s[ct] = zero4;
#pragma unroll
            for (int ct = 0; ct < 4; ++ct) {
                int krow = ct * 16 + ln;
#pragma unroll
                for (int ks = 0; ks < 2; ++ks) {
                    int idx = krow * 64 + (((ks * 4 + blk) ^ (krow & 7)) << 3);
                    f16x8 kf = *(const f16x8*)(Ks + idx);
                    s[ct] = __builtin_amdgcn_mfma_f32_16x16x32_f16(
                        qfh[am][ks], kf, s[ct], 0, 0, 0);
                    s[ct] = __builtin_amdgcn_mfma_f32_16x16x32_f16(
                        qfl[am][ks], kf, s[ct], 0, 0, 0);
                }
            }
            // mask on raw scores (scale folded into exp below)
#pragma unroll
            for (int ct = 0; ct < 4; ++ct) {
                if (mvals[ct] == 0) {
#pragma unroll
                    for (int r = 0; r < 4; ++r) s[ct][r] = -1e20f;
                }
            }
            // online softmax, defer-max (THR=8 in scaled space)
#pragma unroll
            for (int r = 0; r < 4; ++r) {
                float mt = fmaxf(fmaxf(s[0][r], s[1][r]),
                                 fmaxf(s[2][r], s[3][r]));
#pragma unroll
                for (int off = 1; off < 16; off <<= 1)
                    mt = fmaxf(mt, __shfl_xor(mt, off, 16));
                float pmax = mt * 0.03125f;
                if (pmax > m_i[am][r] + 8.f) {
                    float al = __expf(m_i[am][r] - pmax);
                    m_i[am][r] = pmax;
                    l_i[am][r] *= al;
#pragma unroll
                    for (int bn = 0; bn < 4; ++bn) oacc[am][bn][r] *= al;
                }
                float mn = m_i[am][r];
                float rs = 0.f;
#pragma unroll
                for (int ct = 0; ct < 4; ++ct) {
                    float p = __expf(fmaf(s[ct][r], 0.03125f, -mn));
                    s[ct][r] = p;
                    rs += p;
                }
#pragma unroll
                for (int off = 1; off < 16; off <<= 1)
                    rs += __shfl_xor(rs, off, 16);
                l_i[am][r] += rs;
            }
            // ---- P -> f16 -> wave-private LDS (swizzled slots) ----
            u16* P = asmem + 8192 + wid * 1024;
#pragma unroll
            for (int ct = 0; ct < 4; ++ct) {
                int slot = ct * 2 + (ln >> 3);
#pragma unroll
                for (int r = 0; r < 4; ++r) {
                    int q = blk * 4 + r;
                    P[q * 64 + ((slot ^ (q & 7)) << 3) + (ln & 7)] =
                        f16_bits(s[ct][r]);
                }
            }
            // ---- PV: O += P @ V^T (single product) ----
#pragma unroll
            for (int ks = 0; ks < 2; ++ks) {
                int pidx = ln * 64 + (((ks * 4 + blk) ^ (ln & 7)) << 3);
                f16x8 pa = *(const f16x8*)(P + pidx);
#pragma unroll
                for (int bn = 0; bn < 4; ++bn) {
                    int vrow = bn * 16 + ln;
                    int vidx =
                        vrow * 64 + (((ks * 4 + blk) ^ (vrow & 7)) << 3);
                    f16x8 vb = *(const f16x8*)(Vts + vidx);
                    oacc[am][bn] = __builtin_amdgcn_mfma_f32_16x16x32_f16(
                        pa, vb, oacc[am][bn], 0, 0, 0);
                }
            }
        }
    }

    // ---- epilogue: normalize, f16, LDS-bounce to coalesced stores ----
    __syncthreads();
#pragma unroll
    for (int am = 0; am < 2; ++am) {
#pragma unroll
        for (int r = 0; r < 4; ++r) {
            int ql_ = wid * 32 + am * 16 + blk * 4 + r;
            float inv = 1.f / l_i[am][r];
#pragma unroll
            for (int bn = 0; bn < 4; ++bn) {
                int d = bn * 16 + ln;
                asmem[ql_ * OPITCH + d] = f16_bits(oacc[am][bn][r] * inv);
            }
        }
    }
    __syncthreads();
#pragma unroll
    for (int p = 0; p < 4; ++p) {
        int f = p * 256 + t;
        int qq = f >> 3, dc = f & 7;
        short8v rd = *(const short8v*)(asmem + qq * OPITCH + dc * 8);
        *(short8v*)(Ao + (size_t)(b * SEQ + q0 + qq) * DM + h * DK + dc * 8) =
            rd;
    }
}

// ---------------------------------------------------------------------------
extern "C" void kernel_launch(void* const* d_in, const int* in_sizes, int n_in,
                              void* d_out, int out_size, void* d_ws, size_t ws_size,
                              hipStream_t stream)
{
    const float* values = (const float*)d_in[0];
    const float* keys   = (const float*)d_in[1];
    const float* query  = (const float*)d_in[2];
    const int*   mask   = (const int*)d_in[3];
    const float* Wq = (const float*)d_in[4];
    const float* bq = (const float*)d_in[5];
    const float* Wk = (const float*)d_in[6];
    const float* bk = (const float*)d_in[7];
    const float* Wv = (const float*)d_in[8];
    const float* bv = (const float*)d_in[9];
    const float* Wo = (const float*)d_in[10];
    const float* bo = (const float*)d_in[11];
    float* out = (float*)d_out;

    // workspace (u16 units), 144 MB total
    u16* Qh   = (u16*)d_ws;                  // 16 MB
    u16* Ql   = Qh + NQ;                     // 16 MB
    u16* Kf   = Ql + NQ;                     // 16 MB
    u16* Vt   = Kf + NQ;                     // 16 MB
    u16* Wthi = Vt + NQ;                     // 8 MB (4 x [n][k] f16)
    u16* Wtlo = Wthi + (size_t)4 * DM * DM;  // 8 MB
    u16* tAq  = Wtlo + (size_t)4 * DM * DM;  // 16 MB
    u16* tAk  = tAq + NQ;                    // 16 MB
    u16* tAv  = tAk + NQ;                    // 16 MB
    u16* Ao   = tAv + NQ;                    // 16 MB

    const u16* WqH = Wthi + 0 * (size_t)DM * DM;
    const u16* WkH = Wthi + 1 * (size_t)DM * DM;
    const u16* WvH = Wthi + 2 * (size_t)DM * DM;
    const u16* WoH = Wthi + 3 * (size_t)DM * DM;
    const u16* WqL = Wtlo + 0 * (size_t)DM * DM;
    const u16* WkL = Wtlo + 1 * (size_t)DM * DM;
    const u16* WvL = Wtlo + 2 * (size_t)DM * DM;
    const u16* WoL = Wtlo + 3 * (size_t)DM * DM;

    dim3 blk(256);
    conv_w<<<dim3(16, 32, 4), blk, 0, stream>>>(Wq, Wk, Wv, Wo, Wthi, Wtlo);
    conv_cast3<<<dim3((int)(NQ / 2048), 1, 3), blk, 0, stream>>>(
        query, keys, values, tAq, tAk, tAv);
    gemm_qkv<<<dim3(MROWS / 128, DM / 128, 3), blk, 0, stream>>>(
        tAq, tAk, tAv, WqH, WqL, WkH, WkL, WvH, WvL, bq, bk, bv,
        Qh, Ql, Kf, Vt);
    attn_f16<<<dim3(SEQ / 128, NHEADS, NB), blk, 0, stream>>>(
        Qh, Ql, Kf, Vt, mask, Ao);
    gemm_o<<<dim3(MROWS / 128, DM / 128, 1), blk, 0, stream>>>(
        Ao, WoH, WoL, bo, out);
}